// Round 12
// baseline (117.615 us; speedup 1.0000x reference)
//
#include <hip/hip_runtime.h>
#include <hip/hip_fp16.h>

// Ultimus: out = x + softmax((x@Kw+Kb)@(x@Qw+Qb)^T / sqrt(8)) @ (x@Vw+Vb) @ Zw + Zb
// N=8192, D_IN=48, D_ATTN=8, fp32 in/out.
//
// R12 = R7/R11 skeleton (row=lane, 64 rows/block, wave=j-slice, ONE merge)
// with BOTH fixes at once:
//  - loads: LDS tile, staged coalesced once/block (vmcnt-pipelined vector
//    loads), hot loop = wave-uniform ds_read_b128 broadcast (in-order DS,
//    fine-grained lgkmcnt). Kills R7/R11's s_load lgkmcnt(0) serialization
//    and R8's 16-cyc uniform-vector-load broadcast tax.
//  - math: inline-asm v_pk_fma_f16 (17 packed FMAs/pair guaranteed; R10/R11
//    intrinsic paths could not be verified to stay packed).
//  - LDS tile and merge scratch share one 16.4 KB buffer -> 8 blocks/CU.
//
// ws layout (floats):
//   [0, 32768)      Xksf16[8192] 8 f16/row (k * log2e/sqrt(8)), uint4/row
//   [32768, 98304)  QV per pair p: 16 dwords = q2pair[8] | v2pair[8]
//                   (dword c of pair p = half2(val[2p][c], val[2p+1][c]))
//   [98304, 98560)  bmax[256] per-proj-block max ||q||^2 (plain store)
//   [98560, ...)    part[nch][8192][9] f32 partials: acc[0:8], l at [8]

#define QV_OFF   32768
#define BMAX_OFF 98304
#define PART_OFF 98560

typedef _Float16 hv2 __attribute__((ext_vector_type(2)));
union HVU { unsigned u; hv2 v; };

static __device__ __forceinline__ unsigned pku(float a, float b) {
    auto t = __builtin_amdgcn_cvt_pkrtz(a, b);
    union { decltype(t) x; unsigned u; } c; c.x = t; return c.u;
}
static __device__ __forceinline__ hv2 asV(unsigned u) { HVU t; t.u = u; return t.v; }
static __device__ __forceinline__ unsigned dupL(unsigned u) {
    const unsigned lo = u & 0xFFFFu; return lo | (lo << 16);
}
static __device__ __forceinline__ unsigned dupH(unsigned u) {
    const unsigned hi = u >> 16; return hi | (hi << 16);
}
// d += a*b on packed f16 pairs — guaranteed v_pk_fma_f16
static __device__ __forceinline__ void pkfma(unsigned& d, unsigned a, unsigned b) {
    asm("v_pk_fma_f16 %0, %1, %2, %0" : "+v"(d) : "v"(a), "v"(b));
}

__global__ __launch_bounds__(256) void proj_kernel(
    const float* __restrict__ x,
    const float* __restrict__ Kw, const float* __restrict__ Kb,
    const float* __restrict__ Qw, const float* __restrict__ Qb,
    const float* __restrict__ Vw, const float* __restrict__ Vb,
    unsigned* __restrict__ Xksf16, unsigned* __restrict__ QV,
    float* __restrict__ bmax)
{
    __shared__ float xs[32 * 49];     // +1 pad
    __shared__ float wAll[3 * 388];   // stride 388 (mod 32 = 4) spreads 3 mats
    __shared__ float bs[24];
    __shared__ float outv[32][25];    // 24 cols + pad
    const int tid = threadIdx.x;
    const int r0 = blockIdx.x * 32;

    for (int i = tid; i < 1536; i += 256) {
        int r = i / 48, c = i - r * 48;
        xs[r * 49 + c] = x[r0 * 48 + i];
    }
    for (int i = tid; i < 384; i += 256) {
        wAll[i]       = Kw[i];
        wAll[388 + i] = Qw[i];
        wAll[776 + i] = Vw[i];
    }
    if (tid < 8)       bs[tid] = Kb[tid];
    else if (tid < 16) bs[tid] = Qb[tid - 8];
    else if (tid < 24) bs[tid] = Vb[tid - 16];
    __syncthreads();

    const int rl = tid >> 3;
    const int g  = tid & 7;
    const int c0 = 3 * g;
    const float* xr = &xs[rl * 49];
    const float* w0 = &wAll[((c0 + 0) >> 3) * 388 + ((c0 + 0) & 7)];
    const float* w1 = &wAll[((c0 + 1) >> 3) * 388 + ((c0 + 1) & 7)];
    const float* w2 = &wAll[((c0 + 2) >> 3) * 388 + ((c0 + 2) & 7)];
    float a0 = bs[c0], a1 = bs[c0 + 1], a2 = bs[c0 + 2];
    #pragma unroll
    for (int k = 0; k < 48; k++) {
        const float xv = xr[k];
        a0 = fmaf(xv, w0[k * 8], a0);
        a1 = fmaf(xv, w1[k * 8], a1);
        a2 = fmaf(xv, w2[k * 8], a2);
    }
    outv[rl][c0] = a0; outv[rl][c0 + 1] = a1; outv[rl][c0 + 2] = a2;
    __syncthreads();

    // QV pair-interleaved: pair p (16/block), col c (8), m: 0=q, 1=v
    {
        const int p = tid >> 4;
        const int c = (tid >> 1) & 7;
        const int m = tid & 1;
        const int col = (m ? 16 : 8) + c;
        QV[(blockIdx.x * 16 + p) * 16 + m * 8 + c] =
            pku(outv[2 * p][col], outv[2 * p + 1][col]);
    }
    const float kscale = 0.51008732149f;  // (1/sqrt(8)) * log2(e)
    if (tid < 32) {                       // K rows, f16 packed, pre-scaled
        uint4 o;
        o.x = pku(outv[tid][0] * kscale, outv[tid][1] * kscale);
        o.y = pku(outv[tid][2] * kscale, outv[tid][3] * kscale);
        o.z = pku(outv[tid][4] * kscale, outv[tid][5] * kscale);
        o.w = pku(outv[tid][6] * kscale, outv[tid][7] * kscale);
        ((uint4*)Xksf16)[r0 + tid] = o;
    }
    if (tid >= 192 && tid < 224) {        // block-max ||q||^2 (fp32)
        const int r = tid - 192;
        float n2 = 0.f;
        #pragma unroll
        for (int c = 0; c < 8; c++) n2 = fmaf(outv[r][8 + c], outv[r][8 + c], n2);
        #pragma unroll
        for (int off = 16; off > 0; off >>= 1)
            n2 = fmaxf(n2, __shfl_xor(n2, off, 64));
        if (r == 0) bmax[blockIdx.x] = n2;
    }
}

// grid = 128 row-groups (64 rows; row = lane) x nch j-chunks.
// Block stages its 4*ppw-pair QV slice to LDS; wave wv reads pairs
// [wv*ppw, +ppw) via uniform ds_read_b128 (broadcast).
__global__ __launch_bounds__(256) void attn_kernel(
    const unsigned* __restrict__ Xksf16, const unsigned* __restrict__ QV,
    const float* __restrict__ bmax,
    float* __restrict__ part, int ppw)
{
    extern __shared__ char smem[];     // max(tile 4*ppw*64B, red 13312B)
    uint4* tile4 = (uint4*)smem;
    float (*red)[64][13] = (float (*)[64][13])smem;

    const int tid  = threadIdx.x;
    const int lane = tid & 63;
    const int wv   = tid >> 6;
    const int rgrp  = blockIdx.x & 127;
    const int chunk = blockIdx.x >> 7;
    const int row   = rgrp * 64 + lane;
    const int npair = 4 * ppw;

    // stage the block's QV slice: coalesced, vmcnt-pipelined
    for (int i = tid; i < npair * 4; i += 256)
        tile4[i] = ((const uint4*)QV)[(size_t)chunk * npair * 4 + i];

    // qmax2 = max over 256 per-proj-block maxima
    float m = fmaxf(fmaxf(bmax[lane], bmax[64 + lane]),
                    fmaxf(bmax[128 + lane], bmax[192 + lane]));
    #pragma unroll
    for (int off = 32; off > 0; off >>= 1)
        m = fmaxf(m, __shfl_xor(m, off, 64));
    const float qmax2 = m;

    const uint4 kv = ((const uint4*)Xksf16)[row];   // coalesced 16B/lane
    unsigned kd[8];
    kd[0] = dupL(kv.x); kd[1] = dupH(kv.x);
    kd[2] = dupL(kv.y); kd[3] = dupH(kv.y);
    kd[4] = dupL(kv.z); kd[5] = dupH(kv.z);
    kd[6] = dupL(kv.w); kd[7] = dupH(kv.w);
    float kn2 = 0.f;
    #pragma unroll
    for (int c = 0; c < 8; c++) {
        const float kf = (float)asV(kd[c]).x;
        kn2 = fmaf(kf, kf, kn2);
    }
    const float sinit = -sqrtf(kn2 * qmax2);  // s <= -sinit: p in (0,~1]
    const unsigned sinit2 = pku(sinit, sinit);
    const unsigned one2 = 0x3C003C00u;
    unsigned l2 = 0u, acc[8];
    #pragma unroll
    for (int c = 0; c < 8; c++) acc[c] = 0u;

    __syncthreads();                   // tile ready

    const uint4* tw = tile4 + (size_t)wv * ppw * 4;
    #pragma unroll 4
    for (int p = 0; p < ppw; p++) {
        // wave-uniform ds_read_b128 x4: LDS broadcast, in-order, pipelined
        const uint4 qp0 = tw[p * 4 + 0];   // q2pair c0..3
        const uint4 qp1 = tw[p * 4 + 1];   // q2pair c4..7
        const uint4 vp0 = tw[p * 4 + 2];   // v2pair c0..3
        const uint4 vp1 = tw[p * 4 + 3];   // v2pair c4..7
        unsigned s2 = sinit2;
        pkfma(s2, kd[0], qp0.x);
        pkfma(s2, kd[1], qp0.y);
        pkfma(s2, kd[2], qp0.z);
        pkfma(s2, kd[3], qp0.w);
        pkfma(s2, kd[4], qp1.x);
        pkfma(s2, kd[5], qp1.y);
        pkfma(s2, kd[6], qp1.z);
        pkfma(s2, kd[7], qp1.w);
        const hv2 s2v = asV(s2);
        const float pa = __builtin_amdgcn_exp2f((float)s2v.x);
        const float pb = __builtin_amdgcn_exp2f((float)s2v.y);
        const unsigned ph = pku(pa, pb);
        pkfma(l2, ph, one2);
        pkfma(acc[0], ph, vp0.x);
        pkfma(acc[1], ph, vp0.y);
        pkfma(acc[2], ph, vp0.z);
        pkfma(acc[3], ph, vp0.w);
        pkfma(acc[4], ph, vp1.x);
        pkfma(acc[5], ph, vp1.y);
        pkfma(acc[6], ph, vp1.z);
        pkfma(acc[7], ph, vp1.w);
    }

    __syncthreads();                   // all waves done reading tile (aliased)

    // merge the block's 4 waves once via LDS (no atomics, no butterfly)
    #pragma unroll
    for (int c = 0; c < 8; c++) {
        const hv2 a = asV(acc[c]);
        red[wv][lane][c] = (float)a.x + (float)a.y;
    }
    {
        const hv2 lv = asV(l2);
        red[wv][lane][8] = (float)lv.x + (float)lv.y;
    }
    __syncthreads();
    for (int e = tid; e < 576; e += 256) {
        const int r = e / 9, c = e - r * 9;
        const float s = red[0][r][c] + red[1][r][c] + red[2][r][c] + red[3][r][c];
        part[((size_t)chunk * 8192 + rgrp * 64 + r) * 9 + c] = s;
    }
}

__global__ __launch_bounds__(256) void finish_kernel(
    const float* __restrict__ x,
    const float* __restrict__ Zw, const float* __restrict__ Zb,
    const float* __restrict__ part, float* __restrict__ out, int nch)
{
    __shared__ float Zs[128 * 9];
    __shared__ float zw_s[384];
    __shared__ float zb_s[48];
    const int tid = threadIdx.x;
    const int r0 = blockIdx.x * 128;

    for (int i = tid; i < 384; i += 256) zw_s[i] = Zw[i];
    if (tid < 48) zb_s[tid] = Zb[tid];

    if (tid < 128) {
        const int row = r0 + tid;
        float a[9];
        #pragma unroll
        for (int c = 0; c < 9; c++) a[c] = 0.f;
        for (int ch = 0; ch < nch; ch++) {
            const float* p = part + ((size_t)ch * 8192 + row) * 9;
            #pragma unroll
            for (int c = 0; c < 9; c++) a[c] += p[c];
        }
        const float inv = 1.0f / a[8];
        #pragma unroll
        for (int c = 0; c < 8; c++) Zs[tid * 9 + c] = a[c] * inv;
    }
    __syncthreads();

    for (int e = tid; e < 128 * 48; e += 256) {
        const int r = e / 48, c = e - r * 48;
        float o = x[r0 * 48 + e] + zb_s[c];
        #pragma unroll
        for (int k = 0; k < 8; k++) o = fmaf(Zs[r * 9 + k], zw_s[k * 48 + c], o);
        out[r0 * 48 + e] = o;
    }
}

extern "C" void kernel_launch(void* const* d_in, const int* in_sizes, int n_in,
                              void* d_out, int out_size, void* d_ws, size_t ws_size,
                              hipStream_t stream) {
    const float* x  = (const float*)d_in[0];
    const float* Kw = (const float*)d_in[1];
    const float* Kb = (const float*)d_in[2];
    const float* Qw = (const float*)d_in[3];
    const float* Qb = (const float*)d_in[4];
    const float* Vw = (const float*)d_in[5];
    const float* Vb = (const float*)d_in[6];
    const float* Zw = (const float*)d_in[7];
    const float* Zb = (const float*)d_in[8];
    float* out = (float*)d_out;

    float* ws = (float*)d_ws;
    unsigned* Xksf16 = (unsigned*)ws;
    unsigned* QV     = (unsigned*)(ws + QV_OFF);
    float* bmax      = ws + BMAX_OFF;
    float* part      = ws + PART_OFF;

    int nch = 16;
    const size_t avail = ws_size / 4;
    while (nch > 1 && (size_t)PART_OFF + (size_t)nch * 8192 * 9 > avail) nch >>= 1;
    const int ppw = 1024 / nch;   // j-pairs per wave (4096 pairs / (nch*4 waves))

    const int tile_bytes = 4 * ppw * 64;              // QV slice
    const int smem_bytes = tile_bytes > 13312 ? tile_bytes : 13312;

    proj_kernel<<<256, 256, 0, stream>>>(x, Kw, Kb, Qw, Qb, Vw, Vb,
                                         Xksf16, QV, bmax);
    attn_kernel<<<128 * nch, 256, smem_bytes, stream>>>(Xksf16, QV, bmax,
                                                        part, ppw);
    finish_kernel<<<64, 256, 0, stream>>>(x, Zw, Zb, part, out, nch);
}